// Round 20
// baseline (176.544 us; speedup 1.0000x reference)
//
#include <hip/hip_runtime.h>
#include <hip/hip_bf16.h>

#define NN 512
#define NFG 128
#define NFR 64
#define BT 256

typedef __attribute__((ext_vector_type(8))) short bfrag;   // 8 bf16
typedef __attribute__((ext_vector_type(4))) float f32x4;

__device__ __forceinline__ short f2bf(float f) {
    unsigned u = __float_as_uint(f);
    return (short)((u + 0x7fffu + ((u >> 16) & 1u)) >> 16);
}
__device__ __forceinline__ float bf2f(short s) {
    return __uint_as_float(((unsigned)(unsigned short)s) << 16);
}

// ---------------------------------------------------------------------------
// k_prep: WtB[g][f] = bf16(W[f][g])
__global__ __launch_bounds__(256) void k_prep(const float* __restrict__ W,
                                              short* __restrict__ WtB) {
    int i = blockIdx.x * 256 + threadIdx.x;
    if (i < NFG * NFG) { int f = i >> 7, g = i & 127; WtB[g * NFG + f] = f2bf(W[i]); }
}

// ---------------------------------------------------------------------------
// k_projF: theta = (X@thw^T + thb)*0.125 (row layout);
//          phiX  = X@phw^T + phb in FRAGMENT-ORDERED layout (ELEMENT units):
//            element (m,f) -> bt*32768 + (m>>4)*1024 + (f>>5)*512
//                             + (((f&31)>>3)*16 + (m&15))*8 + (f&7)
//          Yt2[c][g][mm] = (X@W)[m][g]  (c=m>>5, mm=m&31)
__global__ __launch_bounds__(256) void k_projF(const float* __restrict__ X,
                                               const float* __restrict__ thw,
                                               const float* __restrict__ thb,
                                               const float* __restrict__ phw,
                                               const float* __restrict__ phb,
                                               const short* __restrict__ WtB,
                                               short* __restrict__ thetaS,
                                               short* __restrict__ phiX,
                                               short* __restrict__ YtG) {
    __shared__ short Xs[64][136];
    __shared__ short wS[2][64][136];
    __shared__ float bS[2][64];
    const int bt = blockIdx.y, bx = blockIdx.x, n0 = bx * 64, tid = threadIdx.x;

    {   // stage X tile (f32 -> bf16)
        int row = tid >> 2, seg = tid & 3;
        const float* src = X + ((size_t)(bt * NN + n0 + row)) * NFG + seg * 32;
        short tmp[32];
        #pragma unroll
        for (int k = 0; k < 8; ++k) {
            float4 v = reinterpret_cast<const float4*>(src)[k];
            tmp[k*4+0] = f2bf(v.x); tmp[k*4+1] = f2bf(v.y);
            tmp[k*4+2] = f2bf(v.z); tmp[k*4+3] = f2bf(v.w);
        }
        #pragma unroll
        for (int k = 0; k < 4; ++k)
            reinterpret_cast<uint4*>(&Xs[row][seg * 32])[k] =
                reinterpret_cast<uint4*>(tmp)[k];
    }
    #pragma unroll
    for (int k = 0; k < 32; ++k) {
        int idx = k * 256 + tid;
        int r = idx >> 7, f = idx & 127;
        wS[0][r][f] = f2bf(thw[idx]);
        wS[1][r][f] = f2bf(phw[idx]);
    }
    if (tid < 64) { bS[0][tid] = thb[tid]; bS[1][tid] = phb[tid]; }
    __syncthreads();

    const int wid = tid >> 6, lane = tid & 63;
    const int l16 = lane & 15, lg = lane >> 4;

    bfrag xa[4];
    #pragma unroll
    for (int kk = 0; kk < 4; ++kk)
        xa[kk] = *reinterpret_cast<const bfrag*>(&Xs[wid * 16 + l16][kk * 32 + lg * 8]);

    for (int pass = 0; pass < 2; ++pass) {
        const float sc = pass ? 1.0f : 0.125f;
        #pragma unroll
        for (int c = 0; c < 4; ++c) {
            f32x4 acc = {0.f, 0.f, 0.f, 0.f};
            #pragma unroll
            for (int kk = 0; kk < 4; ++kk) {
                bfrag b = *reinterpret_cast<const bfrag*>(
                    &wS[pass][c * 16 + l16][kk * 32 + lg * 8]);
                acc = __builtin_amdgcn_mfma_f32_16x16x32_bf16(xa[kk], b, acc, 0, 0, 0);
            }
            float bv = bS[pass][c * 16 + l16];
            if (pass == 0) {
                #pragma unroll
                for (int r = 0; r < 4; ++r) {
                    int n = n0 + wid * 16 + lg * 4 + r;
                    thetaS[((size_t)(bt * NN + n)) * NFR + c * 16 + l16] =
                        f2bf((acc[r] + bv) * sc);
                }
            } else {
                // phiX fragment-ordered store (element strides: tile=1024, half=512)
                const size_t tbase = (size_t)bt * (NN * NFR)
                                   + (size_t)(bx * 4 + wid) * 1024
                                   + (c >> 1) * 512;
                const int lgp = (c & 1) * 2 + (l16 >> 3);
                const int e = l16 & 7;
                #pragma unroll
                for (int r = 0; r < 4; ++r) {
                    phiX[tbase + (size_t)(lgp * 16 + lg * 4 + r) * 8 + e] =
                        f2bf(acc[r] + bv);
                }
            }
        }
    }

    // Yt tiled store: addr = bt*65536 + (c*128 + g)*32 + mm
    const size_t ybase = (size_t)bt * NFG * NN;
    #pragma unroll
    for (int gi = 0; gi < 2; ++gi) {
        int gs = wid * 2 + gi;
        bfrag wa[4];
        #pragma unroll
        for (int kk = 0; kk < 4; ++kk)
            wa[kk] = *reinterpret_cast<const bfrag*>(
                &WtB[(gs * 16 + l16) * NFG + kk * 32 + lg * 8]);
        #pragma unroll
        for (int ms = 0; ms < 4; ++ms) {
            f32x4 acc = {0.f, 0.f, 0.f, 0.f};
            #pragma unroll
            for (int kk = 0; kk < 4; ++kk) {
                bfrag xb = *reinterpret_cast<const bfrag*>(
                    &Xs[ms * 16 + l16][kk * 32 + lg * 8]);
                acc = __builtin_amdgcn_mfma_f32_16x16x32_bf16(wa[kk], xb, acc, 0, 0, 0);
            }
            #pragma unroll
            for (int r = 0; r < 4; ++r) {
                int g = gs * 16 + lg * 4 + r;
                int m = n0 + ms * 16 + l16;
                YtG[ybase + (size_t)((m >> 5) * NFG + g) * 32 + (m & 31)] = f2bf(acc[r]);
            }
        }
    }
}

// ---------------------------------------------------------------------------
// k_fused5 (r19 structure, PLAIN cached stores instead of NT):
//   32-row blocks, 256 threads (ns=wid&1 row-set, mh=wid>>1 m/g half).
//   phase A: QK (depth-4 phi prefetch, 1KB contiguous) + exact mask (LDS
//            centers) + exp -> S (32x512 bf16 swizzled); reg row-sum.
//   phase B: PV (dbuf Yt frags, 1-ahead pa) + rg interleaved.
__global__ __launch_bounds__(256, 4) void k_fused5(const short* __restrict__ thetaS,
                                                   const short* __restrict__ phiX,
                                                   const short* __restrict__ YtG,
                                                   const float* __restrict__ boxes,
                                                   float* __restrict__ outG,
                                                   float* __restrict__ rgG) {
    __shared__ short S[32 * 512];      // 32,768 B (XOR-swizzled 16B granules)
    __shared__ float2 c2s[NN];         //  4,096 B
    __shared__ float partS[2][32];     //    256 B
    const int bid = blockIdx.x;        // 0..4095
    const int jj = bid >> 3;
    const int bt = (bid & 7) * 32 + (jj >> 4);   // 16 blocks/frame on one XCD
    const int n0 = (jj & 15) * 32;
    const int tid = threadIdx.x;
    const int wid = tid >> 6, lane = tid & 63;
    const int l16 = lane & 15, lg = lane >> 4;
    const int ns = wid & 1;            // row subtile (16 rows)
    const int mh = wid >> 1;           // m half (QK) / g half (PV)
    const int r8 = l16 & 7;
    const int nloc = ns * 16 + l16;
    const size_t fr = (size_t)bt * NN;
    const float THR = __uint_as_float(0x43800001u);   // 256 + 2^-15

    {   // centers once per block, coalesced (bit-exact vs numpy f32 RNE)
        #pragma unroll
        for (int k = 0; k < 2; ++k) {
            int row = k * 256 + tid;
            float4 b = reinterpret_cast<const float4*>(boxes)[fr + row];
            c2s[row] = make_float2(__fmul_rn(__fadd_rn(b.x, b.z), 0.5f),
                                   __fmul_rn(__fadd_rn(b.y, b.w), 0.5f));
        }
    }

    // theta B-frags (pre-scaled by 1/8 -> MFMA output IS sim)
    bfrag thB0 = *reinterpret_cast<const bfrag*>(
        &thetaS[(fr + n0 + nloc) * NFR + lg * 8]);
    bfrag thB1 = *reinterpret_cast<const bfrag*>(
        &thetaS[(fr + n0 + nloc) * NFR + 32 + lg * 8]);
    __syncthreads();                                  // barrier 1

    const float2 cn = c2s[n0 + nloc];

    // -------- phase A: QK + mask + exp -> S, depth-4 phi prefetch ---------
    const short* pXf = phiX + (size_t)bt * (NN * NFR)
                     + (size_t)mh * 16 * 1024 + lane * 8;
    bfrag pf0[4], pf1[4];
    #pragma unroll
    for (int t = 0; t < 4; ++t) {
        pf0[t] = *reinterpret_cast<const bfrag*>(pXf + t * 1024);
        pf1[t] = *reinterpret_cast<const bfrag*>(pXf + t * 1024 + 512);
    }
    float smv = 0.f;
    #pragma unroll
    for (int t = 0; t < 16; ++t) {
        bfrag pa0 = pf0[t & 3], pa1 = pf1[t & 3];
        if (t + 4 < 16) {    // issue next tile's loads before consuming this one
            pf0[t & 3] = *reinterpret_cast<const bfrag*>(pXf + (t + 4) * 1024);
            pf1[t & 3] = *reinterpret_cast<const bfrag*>(pXf + (t + 4) * 1024 + 512);
        }
        const int mb = mh * 256 + t * 16;
        f32x4 acc = {0.f, 0.f, 0.f, 0.f};
        __builtin_amdgcn_s_setprio(1);
        acc = __builtin_amdgcn_mfma_f32_16x16x32_bf16(pa0, thB0, acc, 0, 0, 0);
        acc = __builtin_amdgcn_mfma_f32_16x16x32_bf16(pa1, thB1, acc, 0, 0, 0);
        __builtin_amdgcn_s_setprio(0);
        float e[4];
        #pragma unroll
        for (int r = 0; r < 4; ++r) {
            int m = mb + lg * 4 + r;
            float2 cm = c2s[m];
            // masked <=> sqrt_RNE(d2) > 16.0f <=> d2 > 256+2^-15
            float dx = __fsub_rn(cn.x, cm.x), dy = __fsub_rn(cn.y, cm.y);
            float d2 = __fadd_rn(__fmul_rn(dx, dx), __fmul_rn(dy, dy));
            e[r] = (d2 > THR) ? 0.f : __expf(acc[r]);   // no-max-sub: |sim| small
        }
        smv += (e[0] + e[1]) + (e[2] + e[3]);
        unsigned q0, q1;
        asm("v_cvt_pk_bf16_f32 %0, %1, %2" : "=v"(q0) : "v"(e[0]), "v"(e[1]));
        asm("v_cvt_pk_bf16_f32 %0, %1, %2" : "=v"(q1) : "v"(e[2]), "v"(e[3]));
        uint2 qq; qq.x = q0; qq.y = q1;
        const int g = mh * 32 + t * 2 + (lg >> 1);      // 16B granule index
        *reinterpret_cast<uint2*>(
            &S[(nloc << 9) + ((g ^ r8) << 3) + ((lg & 1) << 2)]) = qq;
    }
    // row-sum: reduce over lg within wave, exchange across the 2 m-halves
    smv += __shfl_xor(smv, 16);
    smv += __shfl_xor(smv, 32);
    if (lane < 16) partS[mh][nloc] = smv;
    __syncthreads();                                  // barrier 2 (last)

    const float inv = 1.0f / (partS[0][nloc] + partS[1][nloc]);   // row nloc

    // -------- phase B: PV (dbuf Yt frags, 1-ahead pa) + rg interleaved ----
    f32x4 pool[4];
    #pragma unroll
    for (int gi = 0; gi < 4; ++gi) pool[gi] = f32x4{0.f, 0.f, 0.f, 0.f};
    const short* ybp = YtG + (size_t)bt * NFG * NN
                     + mh * 2048 + l16 * 32 + lg * 8;    // +c*4096 +gi*512
    float* rp = rgG + (fr + n0 + nloc) * NN;

    bfrag yb[2][4];
    #pragma unroll
    for (int gi = 0; gi < 4; ++gi)
        yb[0][gi] = *reinterpret_cast<const bfrag*>(ybp + gi * 512);
    bfrag pa = *reinterpret_cast<const bfrag*>(&S[(nloc << 9) + ((lg ^ r8) << 3)]);

    #pragma unroll
    for (int c = 0; c < 16; ++c) {
        if (c + 1 < 16) {   // prefetch next c's Yt frags + pa before MFMAs
            #pragma unroll
            for (int gi = 0; gi < 4; ++gi)
                yb[(c + 1) & 1][gi] = *reinterpret_cast<const bfrag*>(
                    ybp + (c + 1) * 4096 + gi * 512);
        }
        bfrag pa_cur = pa;
        if (c + 1 < 16)
            pa = *reinterpret_cast<const bfrag*>(
                &S[(nloc << 9) + ((((c + 1) * 4 + lg) ^ r8) << 3)]);
        __builtin_amdgcn_s_setprio(1);
        #pragma unroll
        for (int gi = 0; gi < 4; ++gi)
            pool[gi] = __builtin_amdgcn_mfma_f32_16x16x32_bf16(
                pa_cur, yb[c & 1][gi], pool[gi], 0, 0, 0);
        __builtin_amdgcn_s_setprio(0);
        if (mh == (c >> 3)) {   // the 2 waves sharing this row-set split the c's
            f32x4 aa, bb;
            aa[0] = bf2f(pa_cur[0]) * inv; aa[1] = bf2f(pa_cur[1]) * inv;
            aa[2] = bf2f(pa_cur[2]) * inv; aa[3] = bf2f(pa_cur[3]) * inv;
            bb[0] = bf2f(pa_cur[4]) * inv; bb[1] = bf2f(pa_cur[5]) * inv;
            bb[2] = bf2f(pa_cur[6]) * inv; bb[3] = bf2f(pa_cur[7]) * inv;
            *reinterpret_cast<f32x4*>(rp + c * 32 + lg * 8)     = aa;   // plain store
            *reinterpret_cast<f32x4*>(rp + c * 32 + lg * 8 + 4) = bb;   // plain store
        }
    }

    float iv[4];
    #pragma unroll
    for (int r = 0; r < 4; ++r)
        iv[r] = 1.0f / (partS[0][ns * 16 + lg * 4 + r] + partS[1][ns * 16 + lg * 4 + r]);
    #pragma unroll
    for (int gi = 0; gi < 4; ++gi) {
        #pragma unroll
        for (int r = 0; r < 4; ++r) {
            outG[(fr + n0 + ns * 16 + lg * 4 + r) * NFG + mh * 64 + gi * 16 + l16]
                = pool[gi][r] * iv[r];                                  // plain store
        }
    }
}

// ---------------------------------------------------------------------------
// Fallback path (proven round-4 kernels), used only if ws is too small.
__global__ __launch_bounds__(256) void k_proj(const float* __restrict__ X,
                                              const float* __restrict__ thw,
                                              const float* __restrict__ thb,
                                              const float* __restrict__ phw,
                                              const float* __restrict__ phb,
                                              short* __restrict__ thetaS,
                                              short* __restrict__ phiS) {
    __shared__ short Xs[64][136];
    __shared__ short wS[2][64][136];
    __shared__ float bS[2][64];
    const int bt = blockIdx.y, n0 = blockIdx.x * 64, tid = threadIdx.x;
    {
        int row = tid >> 2, seg = tid & 3;
        const float* src = X + ((size_t)(bt * NN + n0 + row)) * NFG + seg * 32;
        short tmp[32];
        #pragma unroll
        for (int k = 0; k < 8; ++k) {
            float4 v = reinterpret_cast<const float4*>(src)[k];
            tmp[k*4+0] = f2bf(v.x); tmp[k*4+1] = f2bf(v.y);
            tmp[k*4+2] = f2bf(v.z); tmp[k*4+3] = f2bf(v.w);
        }
        #pragma unroll
        for (int k = 0; k < 4; ++k)
            reinterpret_cast<uint4*>(&Xs[row][seg * 32])[k] =
                reinterpret_cast<uint4*>(tmp)[k];
    }
    #pragma unroll
    for (int k = 0; k < 32; ++k) {
        int idx = k * 256 + tid;
        int r = idx >> 7, f = idx & 127;
        wS[0][r][f] = f2bf(thw[idx]);
        wS[1][r][f] = f2bf(phw[idx]);
    }
    if (tid < 64) { bS[0][tid] = thb[tid]; bS[1][tid] = phb[tid]; }
    __syncthreads();
    const int wid = tid >> 6, lane = tid & 63;
    const int l16 = lane & 15, lg = lane >> 4;
    bfrag xa[4];
    #pragma unroll
    for (int kk = 0; kk < 4; ++kk)
        xa[kk] = *reinterpret_cast<const bfrag*>(&Xs[wid * 16 + l16][kk * 32 + lg * 8]);
    for (int pass = 0; pass < 2; ++pass) {
        short* dst = pass ? phiS : thetaS;
        #pragma unroll
        for (int c = 0; c < 4; ++c) {
            f32x4 acc = {0.f, 0.f, 0.f, 0.f};
            #pragma unroll
            for (int kk = 0; kk < 4; ++kk) {
                bfrag b = *reinterpret_cast<const bfrag*>(
                    &wS[pass][c * 16 + l16][kk * 32 + lg * 8]);
                acc = __builtin_amdgcn_mfma_f32_16x16x32_bf16(xa[kk], b, acc, 0, 0, 0);
            }
            float bv = bS[pass][c * 16 + l16];
            #pragma unroll
            for (int r = 0; r < 4; ++r) {
                int n = n0 + wid * 16 + lg * 4 + r;
                dst[((size_t)(bt * NN + n)) * NFR + c * 16 + l16] = f2bf(acc[r] + bv);
            }
        }
    }
}

__global__ __launch_bounds__(512) void k_sim(const short* __restrict__ thetaS,
                                             const short* __restrict__ phiS,
                                             const float* __restrict__ boxes,
                                             float* __restrict__ rgG) {
    __shared__ float S[64][516];
    __shared__ float cxs[NN], cys[NN];
    const int bt = blockIdx.y, n0 = blockIdx.x * 64, tid = threadIdx.x;
    const int wid = tid >> 6, lane = tid & 63;
    const int l16 = lane & 15, lg = lane >> 4;
    const int rsub = wid & 3, ch = wid >> 2;
    {
        float4 b = reinterpret_cast<const float4*>(boxes)[bt * NN + tid];
        cxs[tid] = __fmul_rn(__fadd_rn(b.x, b.z), 0.5f);
        cys[tid] = __fmul_rn(__fadd_rn(b.y, b.w), 0.5f);
    }
    bfrag thA[2];
    #pragma unroll
    for (int kk = 0; kk < 2; ++kk)
        thA[kk] = *reinterpret_cast<const bfrag*>(
            &thetaS[((size_t)(bt * NN + n0 + rsub * 16 + l16)) * NFR + kk * 32 + lg * 8]);
    __syncthreads();
    #pragma unroll 1
    for (int mt = 0; mt < 8; ++mt) {
        int m0 = mt * 64;
        #pragma unroll
        for (int ci = 0; ci < 2; ++ci) {
            int cs = ch * 2 + ci;
            int m = m0 + cs * 16 + l16;
            f32x4 acc = {0.f, 0.f, 0.f, 0.f};
            #pragma unroll
            for (int kk = 0; kk < 2; ++kk) {
                bfrag pb = *reinterpret_cast<const bfrag*>(
                    &phiS[((size_t)(bt * NN + m)) * NFR + kk * 32 + lg * 8]);
                acc = __builtin_amdgcn_mfma_f32_16x16x32_bf16(thA[kk], pb, acc, 0, 0, 0);
            }
            float cxm = cxs[m], cym = cys[m];
            #pragma unroll
            for (int r = 0; r < 4; ++r) {
                int nl = rsub * 16 + lg * 4 + r;
                float dx = __fsub_rn(cxs[n0 + nl], cxm);
                float dy = __fsub_rn(cys[n0 + nl], cym);
                float d2 = __fadd_rn(__fmul_rn(dx, dx), __fmul_rn(dy, dy));
                S[nl][m] = (d2 > __uint_as_float(0x43800001u))
                               ? -__builtin_inff() : acc[r] * 0.125f;
            }
        }
    }
    __syncthreads();
    {
        int row = tid >> 3, j = tid & 7;
        float* Sp = &S[row][j * 64];
        float mx = -__builtin_inff();
        #pragma unroll
        for (int k = 0; k < 16; ++k) {
            float4 v = *reinterpret_cast<float4*>(Sp + k * 4);
            mx = fmaxf(mx, fmaxf(fmaxf(v.x, v.y), fmaxf(v.z, v.w)));
        }
        mx = fmaxf(mx, __shfl_xor(mx, 1));
        mx = fmaxf(mx, __shfl_xor(mx, 2));
        mx = fmaxf(mx, __shfl_xor(mx, 4));
        float sm = 0.f;
        #pragma unroll
        for (int k = 0; k < 16; ++k) {
            float4 v = *reinterpret_cast<float4*>(Sp + k * 4);
            v.x = __expf(v.x - mx); v.y = __expf(v.y - mx);
            v.z = __expf(v.z - mx); v.w = __expf(v.w - mx);
            sm += (v.x + v.y) + (v.z + v.w);
            *reinterpret_cast<float4*>(Sp + k * 4) = v;
        }
        sm += __shfl_xor(sm, 1);
        sm += __shfl_xor(sm, 2);
        sm += __shfl_xor(sm, 4);
        float inv = 1.0f / sm;
        float* rp = rgG + ((size_t)(bt * NN) + n0 + row) * NN + j * 64;
        #pragma unroll
        for (int k = 0; k < 16; ++k) {
            float4 a = *reinterpret_cast<float4*>(Sp + k * 4);
            a.x *= inv; a.y *= inv; a.z *= inv; a.w *= inv;
            *reinterpret_cast<float4*>(rp + k * 4) = a;
        }
    }
}

__global__ __launch_bounds__(256) void k_pool(const float* __restrict__ rgG,
                                              const float* __restrict__ X,
                                              const float* __restrict__ W,
                                              float* __restrict__ outG) {
    __shared__ short Xt[128][72];
    __shared__ short poolS[64][136];
    __shared__ short WtS[128][136];
    const int bt = blockIdx.y, n0 = blockIdx.x * 64, tid = threadIdx.x;
    const int wid = tid >> 6, lane = tid & 63;
    const int l16 = lane & 15, lg = lane >> 4;
    #pragma unroll
    for (int k = 0; k < 64; ++k) {
        int idx = k * 256 + tid;
        int f = idx >> 7, g = idx & 127;
        WtS[g][f] = f2bf(W[idx]);
    }
    f32x4 acc[8];
    #pragma unroll
    for (int ft = 0; ft < 8; ++ft) acc[ft] = f32x4{0.f, 0.f, 0.f, 0.f};
    #pragma unroll 1
    for (int mt = 0; mt < 8; ++mt) {
        __syncthreads();
        {
            int m = tid >> 2, seg = tid & 3;
            const float* src = X + ((size_t)(bt * NN + mt * 64 + m)) * NFG + seg * 32;
            #pragma unroll
            for (int k = 0; k < 8; ++k) {
                float4 v = reinterpret_cast<const float4*>(src)[k];
                int f = seg * 32 + k * 4;
                Xt[f + 0][m] = f2bf(v.x); Xt[f + 1][m] = f2bf(v.y);
                Xt[f + 2][m] = f2bf(v.z); Xt[f + 3][m] = f2bf(v.w);
            }
        }
        bfrag pa[2];
        const float* prow = rgG + ((size_t)(bt * NN + n0 + wid * 16 + l16)) * NN + mt * 64;
        #pragma unroll
        for (int kk = 0; kk < 2; ++kk) {
            float4 a = *reinterpret_cast<const float4*>(prow + kk * 32 + lg * 8);
            float4 b = *reinterpret_cast<const float4*>(prow + kk * 32 + lg * 8 + 4);
            short t[8] = { f2bf(a.x), f2bf(a.y), f2bf(a.z), f2bf(a.w),
                           f2bf(b.x), f2bf(b.y), f2bf(b.z), f2bf(b.w) };
            pa[kk] = *reinterpret_cast<bfrag*>(t);
        }
        __syncthreads();
        #pragma unroll
        for (int ft = 0; ft < 8; ++ft) {
            #pragma unroll
            for (int kk = 0; kk < 2; ++kk) {
                bfrag b = *reinterpret_cast<const bfrag*>(
                    &Xt[ft * 16 + l16][kk * 32 + lg * 8]);
                acc[ft] = __builtin_amdgcn_mfma_f32_16x16x32_bf16(pa[kk], b, acc[ft], 0, 0, 0);
            }
        }
    }
    __syncthreads();
    #pragma unroll
    for (int ft = 0; ft < 8; ++ft)
        #pragma unroll
        for (int r = 0; r < 4; ++r)
            poolS[wid * 16 + lg * 4 + r][ft * 16 + l16] = f2bf(acc[ft][r]);
    __syncthreads();
    bfrag a2[4];
    #pragma unroll
    for (int kk = 0; kk < 4; ++kk)
        a2[kk] = *reinterpret_cast<const bfrag*>(&poolS[wid * 16 + l16][kk * 32 + lg * 8]);
    #pragma unroll
    for (int gt = 0; gt < 8; ++gt) {
        f32x4 o = {0.f, 0.f, 0.f, 0.f};
        #pragma unroll
        for (int kk = 0; kk < 4; ++kk) {
            bfrag b2 = *reinterpret_cast<const bfrag*>(&WtS[gt * 16 + l16][kk * 32 + lg * 8]);
            o = __builtin_amdgcn_mfma_f32_16x16x32_bf16(a2[kk], b2, o, 0, 0, 0);
        }
        #pragma unroll
        for (int r = 0; r < 4; ++r) {
            int n = n0 + wid * 16 + lg * 4 + r;
            outG[((size_t)(bt * NN + n)) * NFG + gt * 16 + l16] = o[r];
        }
    }
}

// ---------------------------------------------------------------------------
extern "C" void kernel_launch(void* const* d_in, const int* in_sizes, int n_in,
                              void* d_out, int out_size, void* d_ws, size_t ws_size,
                              hipStream_t stream) {
    const float* X     = (const float*)d_in[0];
    const float* boxes = (const float*)d_in[1];
    const float* W     = (const float*)d_in[2];
    const float* thw   = (const float*)d_in[3];
    const float* thb   = (const float*)d_in[4];
    const float* phw   = (const float*)d_in[5];
    const float* phb   = (const float*)d_in[6];

    float* outR = (float*)d_out;                       // [256*512][128] f32
    float* rgR  = outR + (size_t)BT * NN * NFG;        // [256*512][512] f32

    const size_t TH = (size_t)BT * NN * NFR * 2;       // 16,777,216 B
    const size_t YT = (size_t)BT * NFG * NN * 2;       // 33,554,432 B
    const size_t WS_NEED = TH * 2 + YT + (size_t)NFG * NFG * 2;   // 67,141,632 B
    if (ws_size >= WS_NEED) {
        char* ws = (char*)d_ws;
        short* thetaS = (short*)(ws);
        short* phiX   = (short*)(ws + TH);
        short* YtG    = (short*)(ws + 2 * TH);
        short* WtB    = (short*)(ws + 2 * TH + YT);
        k_prep  <<<64, 256, 0, stream>>>(W, WtB);
        k_projF <<<dim3(8, BT), 256, 0, stream>>>(X, thw, thb, phw, phb, WtB,
                                                  thetaS, phiX, YtG);
        k_fused5<<<4096, 256, 0, stream>>>(thetaS, phiX, YtG, boxes, outR, rgR);
    } else {
        short* thetaS = (short*)d_out;
        short* phiS   = thetaS + (size_t)BT * NN * NFR;
        k_proj<<<dim3(8, BT), 256, 0, stream>>>(X, thw, thb, phw, phb, thetaS, phiS);
        k_sim <<<dim3(8, BT), 512, 0, stream>>>(thetaS, phiS, boxes, rgR);
        k_pool<<<dim3(8, BT), 256, 0, stream>>>(rgR, X, W, outR);
    }
}

// Round 21
// 152.149 us; speedup vs baseline: 1.1603x; 1.1603x over previous
//
#include <hip/hip_runtime.h>
#include <hip/hip_bf16.h>

#define NN 512
#define NFG 128
#define NFR 64
#define BT 256

typedef __attribute__((ext_vector_type(8))) short bfrag;   // 8 bf16
typedef __attribute__((ext_vector_type(4))) float f32x4;

__device__ __forceinline__ short f2bf(float f) {
    unsigned u = __float_as_uint(f);
    return (short)((u + 0x7fffu + ((u >> 16) & 1u)) >> 16);
}
__device__ __forceinline__ float bf2f(short s) {
    return __uint_as_float(((unsigned)(unsigned short)s) << 16);
}

// ---------------------------------------------------------------------------
// k_prep: WtB[g][f] = bf16(W[f][g])
__global__ __launch_bounds__(256) void k_prep(const float* __restrict__ W,
                                              short* __restrict__ WtB) {
    int i = blockIdx.x * 256 + threadIdx.x;
    if (i < NFG * NFG) { int f = i >> 7, g = i & 127; WtB[g * NFG + f] = f2bf(W[i]); }
}

// ---------------------------------------------------------------------------
// k_projF: theta = (X@thw^T + thb)*0.125 (row layout);
//          phiX  = X@phw^T + phb in FRAGMENT-ORDERED layout (ELEMENT units):
//            element (m,f) -> bt*32768 + (m>>4)*1024 + (f>>5)*512
//                             + (((f&31)>>3)*16 + (m&15))*8 + (f&7)
//          Yt2[c][g][mm] = (X@W)[m][g]  (c=m>>5, mm=m&31)
__global__ __launch_bounds__(256) void k_projF(const float* __restrict__ X,
                                               const float* __restrict__ thw,
                                               const float* __restrict__ thb,
                                               const float* __restrict__ phw,
                                               const float* __restrict__ phb,
                                               const short* __restrict__ WtB,
                                               short* __restrict__ thetaS,
                                               short* __restrict__ phiX,
                                               short* __restrict__ YtG) {
    __shared__ short Xs[64][136];
    __shared__ short wS[2][64][136];
    __shared__ float bS[2][64];
    const int bt = blockIdx.y, bx = blockIdx.x, n0 = bx * 64, tid = threadIdx.x;

    {   // stage X tile (f32 -> bf16)
        int row = tid >> 2, seg = tid & 3;
        const float* src = X + ((size_t)(bt * NN + n0 + row)) * NFG + seg * 32;
        short tmp[32];
        #pragma unroll
        for (int k = 0; k < 8; ++k) {
            float4 v = reinterpret_cast<const float4*>(src)[k];
            tmp[k*4+0] = f2bf(v.x); tmp[k*4+1] = f2bf(v.y);
            tmp[k*4+2] = f2bf(v.z); tmp[k*4+3] = f2bf(v.w);
        }
        #pragma unroll
        for (int k = 0; k < 4; ++k)
            reinterpret_cast<uint4*>(&Xs[row][seg * 32])[k] =
                reinterpret_cast<uint4*>(tmp)[k];
    }
    #pragma unroll
    for (int k = 0; k < 32; ++k) {
        int idx = k * 256 + tid;
        int r = idx >> 7, f = idx & 127;
        wS[0][r][f] = f2bf(thw[idx]);
        wS[1][r][f] = f2bf(phw[idx]);
    }
    if (tid < 64) { bS[0][tid] = thb[tid]; bS[1][tid] = phb[tid]; }
    __syncthreads();

    const int wid = tid >> 6, lane = tid & 63;
    const int l16 = lane & 15, lg = lane >> 4;

    bfrag xa[4];
    #pragma unroll
    for (int kk = 0; kk < 4; ++kk)
        xa[kk] = *reinterpret_cast<const bfrag*>(&Xs[wid * 16 + l16][kk * 32 + lg * 8]);

    for (int pass = 0; pass < 2; ++pass) {
        const float sc = pass ? 1.0f : 0.125f;
        #pragma unroll
        for (int c = 0; c < 4; ++c) {
            f32x4 acc = {0.f, 0.f, 0.f, 0.f};
            #pragma unroll
            for (int kk = 0; kk < 4; ++kk) {
                bfrag b = *reinterpret_cast<const bfrag*>(
                    &wS[pass][c * 16 + l16][kk * 32 + lg * 8]);
                acc = __builtin_amdgcn_mfma_f32_16x16x32_bf16(xa[kk], b, acc, 0, 0, 0);
            }
            float bv = bS[pass][c * 16 + l16];
            if (pass == 0) {
                #pragma unroll
                for (int r = 0; r < 4; ++r) {
                    int n = n0 + wid * 16 + lg * 4 + r;
                    thetaS[((size_t)(bt * NN + n)) * NFR + c * 16 + l16] =
                        f2bf((acc[r] + bv) * sc);
                }
            } else {
                // phiX fragment-ordered store (element strides: tile=1024, half=512)
                const size_t tbase = (size_t)bt * (NN * NFR)
                                   + (size_t)(bx * 4 + wid) * 1024
                                   + (c >> 1) * 512;
                const int lgp = (c & 1) * 2 + (l16 >> 3);
                const int e = l16 & 7;
                #pragma unroll
                for (int r = 0; r < 4; ++r) {
                    phiX[tbase + (size_t)(lgp * 16 + lg * 4 + r) * 8 + e] =
                        f2bf(acc[r] + bv);
                }
            }
        }
    }

    // Yt tiled store: addr = bt*65536 + (c*128 + g)*32 + mm
    const size_t ybase = (size_t)bt * NFG * NN;
    #pragma unroll
    for (int gi = 0; gi < 2; ++gi) {
        int gs = wid * 2 + gi;
        bfrag wa[4];
        #pragma unroll
        for (int kk = 0; kk < 4; ++kk)
            wa[kk] = *reinterpret_cast<const bfrag*>(
                &WtB[(gs * 16 + l16) * NFG + kk * 32 + lg * 8]);
        #pragma unroll
        for (int ms = 0; ms < 4; ++ms) {
            f32x4 acc = {0.f, 0.f, 0.f, 0.f};
            #pragma unroll
            for (int kk = 0; kk < 4; ++kk) {
                bfrag xb = *reinterpret_cast<const bfrag*>(
                    &Xs[ms * 16 + l16][kk * 32 + lg * 8]);
                acc = __builtin_amdgcn_mfma_f32_16x16x32_bf16(wa[kk], xb, acc, 0, 0, 0);
            }
            #pragma unroll
            for (int r = 0; r < 4; ++r) {
                int g = gs * 16 + lg * 4 + r;
                int m = n0 + ms * 16 + l16;
                YtG[ybase + (size_t)((m >> 5) * NFG + g) * 32 + (m & 31)] = f2bf(acc[r]);
            }
        }
    }
}

// ---------------------------------------------------------------------------
// k_fused5 (BEST, r19): 32-row blocks, 256 threads (ns=wid&1 row-set,
//   mh=wid>>1 m/g half), NT stores for rg/out.  2 barriers.
//   phase A: QK (depth-4 phi prefetch, 1KB contiguous) + exact mask (LDS
//            centers) + exp -> S (32x512 bf16 swizzled); reg row-sum.
//   phase B: PV (dbuf Yt frags, 1-ahead pa) + rg interleaved (NT stores).
__global__ __launch_bounds__(256, 4) void k_fused5(const short* __restrict__ thetaS,
                                                   const short* __restrict__ phiX,
                                                   const short* __restrict__ YtG,
                                                   const float* __restrict__ boxes,
                                                   float* __restrict__ outG,
                                                   float* __restrict__ rgG) {
    __shared__ short S[32 * 512];      // 32,768 B (XOR-swizzled 16B granules)
    __shared__ float2 c2s[NN];         //  4,096 B
    __shared__ float partS[2][32];     //    256 B
    const int bid = blockIdx.x;        // 0..4095
    const int jj = bid >> 3;
    const int bt = (bid & 7) * 32 + (jj >> 4);   // 16 blocks/frame on one XCD
    const int n0 = (jj & 15) * 32;
    const int tid = threadIdx.x;
    const int wid = tid >> 6, lane = tid & 63;
    const int l16 = lane & 15, lg = lane >> 4;
    const int ns = wid & 1;            // row subtile (16 rows)
    const int mh = wid >> 1;           // m half (QK) / g half (PV)
    const int r8 = l16 & 7;
    const int nloc = ns * 16 + l16;
    const size_t fr = (size_t)bt * NN;
    const float THR = __uint_as_float(0x43800001u);   // 256 + 2^-15

    {   // centers once per block, coalesced (bit-exact vs numpy f32 RNE)
        #pragma unroll
        for (int k = 0; k < 2; ++k) {
            int row = k * 256 + tid;
            float4 b = reinterpret_cast<const float4*>(boxes)[fr + row];
            c2s[row] = make_float2(__fmul_rn(__fadd_rn(b.x, b.z), 0.5f),
                                   __fmul_rn(__fadd_rn(b.y, b.w), 0.5f));
        }
    }

    // theta B-frags (pre-scaled by 1/8 -> MFMA output IS sim)
    bfrag thB0 = *reinterpret_cast<const bfrag*>(
        &thetaS[(fr + n0 + nloc) * NFR + lg * 8]);
    bfrag thB1 = *reinterpret_cast<const bfrag*>(
        &thetaS[(fr + n0 + nloc) * NFR + 32 + lg * 8]);
    __syncthreads();                                  // barrier 1

    const float2 cn = c2s[n0 + nloc];

    // -------- phase A: QK + mask + exp -> S, depth-4 phi prefetch ---------
    const short* pXf = phiX + (size_t)bt * (NN * NFR)
                     + (size_t)mh * 16 * 1024 + lane * 8;
    bfrag pf0[4], pf1[4];
    #pragma unroll
    for (int t = 0; t < 4; ++t) {
        pf0[t] = *reinterpret_cast<const bfrag*>(pXf + t * 1024);
        pf1[t] = *reinterpret_cast<const bfrag*>(pXf + t * 1024 + 512);
    }
    float smv = 0.f;
    #pragma unroll
    for (int t = 0; t < 16; ++t) {
        bfrag pa0 = pf0[t & 3], pa1 = pf1[t & 3];
        if (t + 4 < 16) {    // issue next tile's loads before consuming this one
            pf0[t & 3] = *reinterpret_cast<const bfrag*>(pXf + (t + 4) * 1024);
            pf1[t & 3] = *reinterpret_cast<const bfrag*>(pXf + (t + 4) * 1024 + 512);
        }
        const int mb = mh * 256 + t * 16;
        f32x4 acc = {0.f, 0.f, 0.f, 0.f};
        __builtin_amdgcn_s_setprio(1);
        acc = __builtin_amdgcn_mfma_f32_16x16x32_bf16(pa0, thB0, acc, 0, 0, 0);
        acc = __builtin_amdgcn_mfma_f32_16x16x32_bf16(pa1, thB1, acc, 0, 0, 0);
        __builtin_amdgcn_s_setprio(0);
        float e[4];
        #pragma unroll
        for (int r = 0; r < 4; ++r) {
            int m = mb + lg * 4 + r;
            float2 cm = c2s[m];
            // masked <=> sqrt_RNE(d2) > 16.0f <=> d2 > 256+2^-15
            float dx = __fsub_rn(cn.x, cm.x), dy = __fsub_rn(cn.y, cm.y);
            float d2 = __fadd_rn(__fmul_rn(dx, dx), __fmul_rn(dy, dy));
            e[r] = (d2 > THR) ? 0.f : __expf(acc[r]);   // no-max-sub: |sim| small
        }
        smv += (e[0] + e[1]) + (e[2] + e[3]);
        unsigned q0, q1;
        asm("v_cvt_pk_bf16_f32 %0, %1, %2" : "=v"(q0) : "v"(e[0]), "v"(e[1]));
        asm("v_cvt_pk_bf16_f32 %0, %1, %2" : "=v"(q1) : "v"(e[2]), "v"(e[3]));
        uint2 qq; qq.x = q0; qq.y = q1;
        const int g = mh * 32 + t * 2 + (lg >> 1);      // 16B granule index
        *reinterpret_cast<uint2*>(
            &S[(nloc << 9) + ((g ^ r8) << 3) + ((lg & 1) << 2)]) = qq;
    }
    // row-sum: reduce over lg within wave, exchange across the 2 m-halves
    smv += __shfl_xor(smv, 16);
    smv += __shfl_xor(smv, 32);
    if (lane < 16) partS[mh][nloc] = smv;
    __syncthreads();                                  // barrier 2 (last)

    const float inv = 1.0f / (partS[0][nloc] + partS[1][nloc]);   // row nloc

    // -------- phase B: PV (dbuf Yt frags, 1-ahead pa) + rg interleaved ----
    f32x4 pool[4];
    #pragma unroll
    for (int gi = 0; gi < 4; ++gi) pool[gi] = f32x4{0.f, 0.f, 0.f, 0.f};
    const short* ybp = YtG + (size_t)bt * NFG * NN
                     + mh * 2048 + l16 * 32 + lg * 8;    // +c*4096 +gi*512
    float* rp = rgG + (fr + n0 + nloc) * NN;

    bfrag yb[2][4];
    #pragma unroll
    for (int gi = 0; gi < 4; ++gi)
        yb[0][gi] = *reinterpret_cast<const bfrag*>(ybp + gi * 512);
    bfrag pa = *reinterpret_cast<const bfrag*>(&S[(nloc << 9) + ((lg ^ r8) << 3)]);

    #pragma unroll
    for (int c = 0; c < 16; ++c) {
        if (c + 1 < 16) {   // prefetch next c's Yt frags + pa before MFMAs
            #pragma unroll
            for (int gi = 0; gi < 4; ++gi)
                yb[(c + 1) & 1][gi] = *reinterpret_cast<const bfrag*>(
                    ybp + (c + 1) * 4096 + gi * 512);
        }
        bfrag pa_cur = pa;
        if (c + 1 < 16)
            pa = *reinterpret_cast<const bfrag*>(
                &S[(nloc << 9) + ((((c + 1) * 4 + lg) ^ r8) << 3)]);
        __builtin_amdgcn_s_setprio(1);
        #pragma unroll
        for (int gi = 0; gi < 4; ++gi)
            pool[gi] = __builtin_amdgcn_mfma_f32_16x16x32_bf16(
                pa_cur, yb[c & 1][gi], pool[gi], 0, 0, 0);
        __builtin_amdgcn_s_setprio(0);
        if (mh == (c >> 3)) {   // the 2 waves sharing this row-set split the c's
            f32x4 aa, bb;
            aa[0] = bf2f(pa_cur[0]) * inv; aa[1] = bf2f(pa_cur[1]) * inv;
            aa[2] = bf2f(pa_cur[2]) * inv; aa[3] = bf2f(pa_cur[3]) * inv;
            bb[0] = bf2f(pa_cur[4]) * inv; bb[1] = bf2f(pa_cur[5]) * inv;
            bb[2] = bf2f(pa_cur[6]) * inv; bb[3] = bf2f(pa_cur[7]) * inv;
            __builtin_nontemporal_store(aa,
                reinterpret_cast<f32x4*>(rp + c * 32 + lg * 8));
            __builtin_nontemporal_store(bb,
                reinterpret_cast<f32x4*>(rp + c * 32 + lg * 8 + 4));
        }
    }

    float iv[4];
    #pragma unroll
    for (int r = 0; r < 4; ++r)
        iv[r] = 1.0f / (partS[0][ns * 16 + lg * 4 + r] + partS[1][ns * 16 + lg * 4 + r]);
    #pragma unroll
    for (int gi = 0; gi < 4; ++gi) {
        #pragma unroll
        for (int r = 0; r < 4; ++r) {
            __builtin_nontemporal_store(pool[gi][r] * iv[r],
                &outG[(fr + n0 + ns * 16 + lg * 4 + r) * NFG + mh * 64 + gi * 16 + l16]);
        }
    }
}

// ---------------------------------------------------------------------------
// Fallback path (proven round-4 kernels), used only if ws is too small.
__global__ __launch_bounds__(256) void k_proj(const float* __restrict__ X,
                                              const float* __restrict__ thw,
                                              const float* __restrict__ thb,
                                              const float* __restrict__ phw,
                                              const float* __restrict__ phb,
                                              short* __restrict__ thetaS,
                                              short* __restrict__ phiS) {
    __shared__ short Xs[64][136];
    __shared__ short wS[2][64][136];
    __shared__ float bS[2][64];
    const int bt = blockIdx.y, n0 = blockIdx.x * 64, tid = threadIdx.x;
    {
        int row = tid >> 2, seg = tid & 3;
        const float* src = X + ((size_t)(bt * NN + n0 + row)) * NFG + seg * 32;
        short tmp[32];
        #pragma unroll
        for (int k = 0; k < 8; ++k) {
            float4 v = reinterpret_cast<const float4*>(src)[k];
            tmp[k*4+0] = f2bf(v.x); tmp[k*4+1] = f2bf(v.y);
            tmp[k*4+2] = f2bf(v.z); tmp[k*4+3] = f2bf(v.w);
        }
        #pragma unroll
        for (int k = 0; k < 4; ++k)
            reinterpret_cast<uint4*>(&Xs[row][seg * 32])[k] =
                reinterpret_cast<uint4*>(tmp)[k];
    }
    #pragma unroll
    for (int k = 0; k < 32; ++k) {
        int idx = k * 256 + tid;
        int r = idx >> 7, f = idx & 127;
        wS[0][r][f] = f2bf(thw[idx]);
        wS[1][r][f] = f2bf(phw[idx]);
    }
    if (tid < 64) { bS[0][tid] = thb[tid]; bS[1][tid] = phb[tid]; }
    __syncthreads();
    const int wid = tid >> 6, lane = tid & 63;
    const int l16 = lane & 15, lg = lane >> 4;
    bfrag xa[4];
    #pragma unroll
    for (int kk = 0; kk < 4; ++kk)
        xa[kk] = *reinterpret_cast<const bfrag*>(&Xs[wid * 16 + l16][kk * 32 + lg * 8]);
    for (int pass = 0; pass < 2; ++pass) {
        short* dst = pass ? phiS : thetaS;
        #pragma unroll
        for (int c = 0; c < 4; ++c) {
            f32x4 acc = {0.f, 0.f, 0.f, 0.f};
            #pragma unroll
            for (int kk = 0; kk < 4; ++kk) {
                bfrag b = *reinterpret_cast<const bfrag*>(
                    &wS[pass][c * 16 + l16][kk * 32 + lg * 8]);
                acc = __builtin_amdgcn_mfma_f32_16x16x32_bf16(xa[kk], b, acc, 0, 0, 0);
            }
            float bv = bS[pass][c * 16 + l16];
            #pragma unroll
            for (int r = 0; r < 4; ++r) {
                int n = n0 + wid * 16 + lg * 4 + r;
                dst[((size_t)(bt * NN + n)) * NFR + c * 16 + l16] = f2bf(acc[r] + bv);
            }
        }
    }
}

__global__ __launch_bounds__(512) void k_sim(const short* __restrict__ thetaS,
                                             const short* __restrict__ phiS,
                                             const float* __restrict__ boxes,
                                             float* __restrict__ rgG) {
    __shared__ float S[64][516];
    __shared__ float cxs[NN], cys[NN];
    const int bt = blockIdx.y, n0 = blockIdx.x * 64, tid = threadIdx.x;
    const int wid = tid >> 6, lane = tid & 63;
    const int l16 = lane & 15, lg = lane >> 4;
    const int rsub = wid & 3, ch = wid >> 2;
    {
        float4 b = reinterpret_cast<const float4*>(boxes)[bt * NN + tid];
        cxs[tid] = __fmul_rn(__fadd_rn(b.x, b.z), 0.5f);
        cys[tid] = __fmul_rn(__fadd_rn(b.y, b.w), 0.5f);
    }
    bfrag thA[2];
    #pragma unroll
    for (int kk = 0; kk < 2; ++kk)
        thA[kk] = *reinterpret_cast<const bfrag*>(
            &thetaS[((size_t)(bt * NN + n0 + rsub * 16 + l16)) * NFR + kk * 32 + lg * 8]);
    __syncthreads();
    #pragma unroll 1
    for (int mt = 0; mt < 8; ++mt) {
        int m0 = mt * 64;
        #pragma unroll
        for (int ci = 0; ci < 2; ++ci) {
            int cs = ch * 2 + ci;
            int m = m0 + cs * 16 + l16;
            f32x4 acc = {0.f, 0.f, 0.f, 0.f};
            #pragma unroll
            for (int kk = 0; kk < 2; ++kk) {
                bfrag pb = *reinterpret_cast<const bfrag*>(
                    &phiS[((size_t)(bt * NN + m)) * NFR + kk * 32 + lg * 8]);
                acc = __builtin_amdgcn_mfma_f32_16x16x32_bf16(thA[kk], pb, acc, 0, 0, 0);
            }
            float cxm = cxs[m], cym = cys[m];
            #pragma unroll
            for (int r = 0; r < 4; ++r) {
                int nl = rsub * 16 + lg * 4 + r;
                float dx = __fsub_rn(cxs[n0 + nl], cxm);
                float dy = __fsub_rn(cys[n0 + nl], cym);
                float d2 = __fadd_rn(__fmul_rn(dx, dx), __fmul_rn(dy, dy));
                S[nl][m] = (d2 > __uint_as_float(0x43800001u))
                               ? -__builtin_inff() : acc[r] * 0.125f;
            }
        }
    }
    __syncthreads();
    {
        int row = tid >> 3, j = tid & 7;
        float* Sp = &S[row][j * 64];
        float mx = -__builtin_inff();
        #pragma unroll
        for (int k = 0; k < 16; ++k) {
            float4 v = *reinterpret_cast<float4*>(Sp + k * 4);
            mx = fmaxf(mx, fmaxf(fmaxf(v.x, v.y), fmaxf(v.z, v.w)));
        }
        mx = fmaxf(mx, __shfl_xor(mx, 1));
        mx = fmaxf(mx, __shfl_xor(mx, 2));
        mx = fmaxf(mx, __shfl_xor(mx, 4));
        float sm = 0.f;
        #pragma unroll
        for (int k = 0; k < 16; ++k) {
            float4 v = *reinterpret_cast<float4*>(Sp + k * 4);
            v.x = __expf(v.x - mx); v.y = __expf(v.y - mx);
            v.z = __expf(v.z - mx); v.w = __expf(v.w - mx);
            sm += (v.x + v.y) + (v.z + v.w);
            *reinterpret_cast<float4*>(Sp + k * 4) = v;
        }
        sm += __shfl_xor(sm, 1);
        sm += __shfl_xor(sm, 2);
        sm += __shfl_xor(sm, 4);
        float inv = 1.0f / sm;
        float* rp = rgG + ((size_t)(bt * NN) + n0 + row) * NN + j * 64;
        #pragma unroll
        for (int k = 0; k < 16; ++k) {
            float4 a = *reinterpret_cast<float4*>(Sp + k * 4);
            a.x *= inv; a.y *= inv; a.z *= inv; a.w *= inv;
            *reinterpret_cast<float4*>(rp + k * 4) = a;
        }
    }
}

__global__ __launch_bounds__(256) void k_pool(const float* __restrict__ rgG,
                                              const float* __restrict__ X,
                                              const float* __restrict__ W,
                                              float* __restrict__ outG) {
    __shared__ short Xt[128][72];
    __shared__ short poolS[64][136];
    __shared__ short WtS[128][136];
    const int bt = blockIdx.y, n0 = blockIdx.x * 64, tid = threadIdx.x;
    const int wid = tid >> 6, lane = tid & 63;
    const int l16 = lane & 15, lg = lane >> 4;
    #pragma unroll
    for (int k = 0; k < 64; ++k) {
        int idx = k * 256 + tid;
        int f = idx >> 7, g = idx & 127;
        WtS[g][f] = f2bf(W[idx]);
    }
    f32x4 acc[8];
    #pragma unroll
    for (int ft = 0; ft < 8; ++ft) acc[ft] = f32x4{0.f, 0.f, 0.f, 0.f};
    #pragma unroll 1
    for (int mt = 0; mt < 8; ++mt) {
        __syncthreads();
        {
            int m = tid >> 2, seg = tid & 3;
            const float* src = X + ((size_t)(bt * NN + mt * 64 + m)) * NFG + seg * 32;
            #pragma unroll
            for (int k = 0; k < 8; ++k) {
                float4 v = reinterpret_cast<const float4*>(src)[k];
                int f = seg * 32 + k * 4;
                Xt[f + 0][m] = f2bf(v.x); Xt[f + 1][m] = f2bf(v.y);
                Xt[f + 2][m] = f2bf(v.z); Xt[f + 3][m] = f2bf(v.w);
            }
        }
        bfrag pa[2];
        const float* prow = rgG + ((size_t)(bt * NN + n0 + wid * 16 + l16)) * NN + mt * 64;
        #pragma unroll
        for (int kk = 0; kk < 2; ++kk) {
            float4 a = *reinterpret_cast<const float4*>(prow + kk * 32 + lg * 8);
            float4 b = *reinterpret_cast<const float4*>(prow + kk * 32 + lg * 8 + 4);
            short t[8] = { f2bf(a.x), f2bf(a.y), f2bf(a.z), f2bf(a.w),
                           f2bf(b.x), f2bf(b.y), f2bf(b.z), f2bf(b.w) };
            pa[kk] = *reinterpret_cast<bfrag*>(t);
        }
        __syncthreads();
        #pragma unroll
        for (int ft = 0; ft < 8; ++ft) {
            #pragma unroll
            for (int kk = 0; kk < 2; ++kk) {
                bfrag b = *reinterpret_cast<const bfrag*>(
                    &Xt[ft * 16 + l16][kk * 32 + lg * 8]);
                acc[ft] = __builtin_amdgcn_mfma_f32_16x16x32_bf16(pa[kk], b, acc[ft], 0, 0, 0);
            }
        }
    }
    __syncthreads();
    #pragma unroll
    for (int ft = 0; ft < 8; ++ft)
        #pragma unroll
        for (int r = 0; r < 4; ++r)
            poolS[wid * 16 + lg * 4 + r][ft * 16 + l16] = f2bf(acc[ft][r]);
    __syncthreads();
    bfrag a2[4];
    #pragma unroll
    for (int kk = 0; kk < 4; ++kk)
        a2[kk] = *reinterpret_cast<const bfrag*>(&poolS[wid * 16 + l16][kk * 32 + lg * 8]);
    #pragma unroll
    for (int gt = 0; gt < 8; ++gt) {
        f32x4 o = {0.f, 0.f, 0.f, 0.f};
        #pragma unroll
        for (int kk = 0; kk < 4; ++kk) {
            bfrag b2 = *reinterpret_cast<const bfrag*>(&WtS[gt * 16 + l16][kk * 32 + lg * 8]);
            o = __builtin_amdgcn_mfma_f32_16x16x32_bf16(a2[kk], b2, o, 0, 0, 0);
        }
        #pragma unroll
        for (int r = 0; r < 4; ++r) {
            int n = n0 + wid * 16 + lg * 4 + r;
            outG[((size_t)(bt * NN + n)) * NFG + gt * 16 + l16] = o[r];
        }
    }
}

// ---------------------------------------------------------------------------
extern "C" void kernel_launch(void* const* d_in, const int* in_sizes, int n_in,
                              void* d_out, int out_size, void* d_ws, size_t ws_size,
                              hipStream_t stream) {
    const float* X     = (const float*)d_in[0];
    const float* boxes = (const float*)d_in[1];
    const float* W     = (const float*)d_in[2];
    const float* thw   = (const float*)d_in[3];
    const float* thb   = (const float*)d_in[4];
    const float* phw   = (const float*)d_in[5];
    const float* phb   = (const float*)d_in[6];

    float* outR = (float*)d_out;                       // [256*512][128] f32
    float* rgR  = outR + (size_t)BT * NN * NFG;        // [256*512][512] f32

    const size_t TH = (size_t)BT * NN * NFR * 2;       // 16,777,216 B
    const size_t YT = (size_t)BT * NFG * NN * 2;       // 33,554,432 B
    const size_t WS_NEED = TH * 2 + YT + (size_t)NFG * NFG * 2;   // 67,141,632 B
    if (ws_size >= WS_NEED) {
        char* ws = (char*)d_ws;
        short* thetaS = (short*)(ws);
        short* phiX   = (short*)(ws + TH);
        short* YtG    = (short*)(ws + 2 * TH);
        short* WtB    = (short*)(ws + 2 * TH + YT);
        k_prep  <<<64, 256, 0, stream>>>(W, WtB);
        k_projF <<<dim3(8, BT), 256, 0, stream>>>(X, thw, thb, phw, phb, WtB,
                                                  thetaS, phiX, YtG);
        k_fused5<<<4096, 256, 0, stream>>>(thetaS, phiX, YtG, boxes, outR, rgR);
    } else {
        short* thetaS = (short*)d_out;
        short* phiS   = thetaS + (size_t)BT * NN * NFR;
        k_proj<<<dim3(8, BT), 256, 0, stream>>>(X, thw, thb, phw, phb, thetaS, phiS);
        k_sim <<<dim3(8, BT), 512, 0, stream>>>(thetaS, phiS, boxes, rgR);
        k_pool<<<dim3(8, BT), 256, 0, stream>>>(rgR, X, W, outR);
    }
}